// Round 2
// baseline (81.128 us; speedup 1.0000x reference)
//
#include <hip/hip_runtime.h>

// ConvCaps2D with dynamic routing, fused single kernel.
// B=8, H=W=32, Cin=16, pose 4x4, 3x3 stride-2 VALID -> oh=ow=15,
// O=16 out channels, N=144 votes (padded to 160), 3 routing iterations.
// One block (512 threads) per site: thread t owns (o = t>>5, n = (t&31)+32j,
// j=0..4) -> 5 votes x 16 f32 in registers (~115 persistent VGPRs).

#define OH 15
#define OW 15
#define N_VOTES 144
#define VPT 5            // votes per thread: 160/32
#define POSE_PAD 20      // LDS row stride for pose rows (16 floats + pad)
#define B_PAD 17         // LDS row stride for b[n][o]

__global__ __launch_bounds__(512, 4)
void convcaps_routing_kernel(const float* __restrict__ poses,
                             const float* __restrict__ kern,
                             float* __restrict__ out)
{
    __shared__ float pose_lds[N_VOTES * POSE_PAD]; // 11520 B
    __shared__ float b_lds[N_VOTES * B_PAD];       // 9792 B
    __shared__ float nmax[N_VOTES];                // softmax max per n
    __shared__ float rden[N_VOTES];                // 1/sum(exp) per n

    const int site = blockIdx.x;                   // 0..1799
    const int b    = site / (OH * OW);
    const int rem  = site % (OH * OW);
    const int h    = rem / OW;
    const int w    = rem % OW;

    const int t  = threadIdx.x;
    const int o  = t >> 5;                         // output channel 0..15
    const int nt = t & 31;                         // lane within o-group

    // ---- stage 144 pose matrices (16 f32 each) into LDS, float4 coalesced ----
    // poses[b][y][x][c][p][q], y = 2h+k, x = 2w+l, n = (3k+l)*16 + c
    const float* pbase = poses + (size_t)b * (32 * 32 * 256);
    for (int idx = t; idx < N_VOTES * 4; idx += 512) {
        int n  = idx >> 2;
        int e4 = idx & 3;
        int kl = n >> 4;          // 0..8
        int c  = n & 15;
        int k  = kl / 3, l = kl % 3;
        int y  = 2 * h + k, x = 2 * w + l;
        const float4 v = *reinterpret_cast<const float4*>(
            pbase + (size_t)(y * 32 + x) * 256 + c * 16 + e4 * 4);
        *reinterpret_cast<float4*>(&pose_lds[n * POSE_PAD + e4 * 4]) = v;
    }
    __syncthreads();

    // ---- votes into registers: vote[p][r] = sum_q pose[p][q] * K[q][r] ----
    // j<4 always real (n<=127); j==4 real iff nt<16 (n=128+nt < 144)
    float vreg[VPT][16];
    #pragma unroll
    for (int j = 0; j < VPT; ++j) {
        const int n = nt + 32 * j;
        const bool real = (j < 4) || (nt < 16);
        if (real) {
            const float* Kp = kern + ((size_t)(o * N_VOTES + n) << 4);
            const float4 k0 = reinterpret_cast<const float4*>(Kp)[0];
            const float4 k1 = reinterpret_cast<const float4*>(Kp)[1];
            const float4 k2 = reinterpret_cast<const float4*>(Kp)[2];
            const float4 k3 = reinterpret_cast<const float4*>(Kp)[3];
            const float* P = &pose_lds[n * POSE_PAD];
            #pragma unroll
            for (int p = 0; p < 4; ++p) {
                const float p0 = P[p * 4 + 0], p1 = P[p * 4 + 1];
                const float p2 = P[p * 4 + 2], p3 = P[p * 4 + 3];
                vreg[j][p * 4 + 0] = p0 * k0.x + p1 * k1.x + p2 * k2.x + p3 * k3.x;
                vreg[j][p * 4 + 1] = p0 * k0.y + p1 * k1.y + p2 * k2.y + p3 * k3.y;
                vreg[j][p * 4 + 2] = p0 * k0.z + p1 * k1.z + p2 * k2.z + p3 * k3.z;
                vreg[j][p * 4 + 3] = p0 * k0.w + p1 * k1.w + p2 * k2.w + p3 * k3.w;
            }
        } else {
            #pragma unroll
            for (int e = 0; e < 16; ++e) vreg[j][e] = 0.0f;
        }
    }

    float breg[VPT];
    #pragma unroll
    for (int j = 0; j < VPT; ++j) breg[j] = 0.0f;

    float s[16];   // doubles as v (squashed) after the squash step

    #pragma unroll
    for (int iter = 0; iter < 3; ++iter) {
        // s[o] = sum_n c*vote, c = softmax_o(b)
        #pragma unroll
        for (int e = 0; e < 16; ++e) s[e] = 0.0f;
        #pragma unroll
        for (int j = 0; j < VPT; ++j) {
            const int n = nt + 32 * j;
            const bool real = (j < 4) || (nt < 16);
            float c;
            if (iter == 0) c = 1.0f / 16.0f;               // softmax of zeros
            else           c = real ? __expf(breg[j] - nmax[n]) * rden[n] : 0.0f;
            #pragma unroll
            for (int e = 0; e < 16; ++e) s[e] += c * vreg[j][e];
        }
        // reduce across the 32 lanes of this o-group
        #pragma unroll
        for (int m = 1; m <= 16; m <<= 1) {
            #pragma unroll
            for (int e = 0; e < 16; ++e) s[e] += __shfl_xor(s[e], m, 64);
        }

        // squash: v = s * (sq/(1+sq)) / sqrt(sq + 1e-9)
        float sq = 0.0f;
        #pragma unroll
        for (int e = 0; e < 16; ++e) sq += s[e] * s[e];
        const float factor = (sq / (1.0f + sq)) * rsqrtf(sq + 1e-9f);
        #pragma unroll
        for (int e = 0; e < 16; ++e) s[e] *= factor;

        if (iter < 2) {
            // b[o][n] += dot(v[o], vote[o][n]); publish b for softmax stats
            #pragma unroll
            for (int j = 0; j < VPT; ++j) {
                float d = 0.0f;
                #pragma unroll
                for (int e = 0; e < 16; ++e) d += s[e] * vreg[j][e];
                breg[j] += d;
                const int n = nt + 32 * j;
                const bool real = (j < 4) || (nt < 16);
                if (real) b_lds[n * B_PAD + o] = breg[j];
            }
            __syncthreads();
            if (t < N_VOTES) {
                float mx = -1e30f;
                #pragma unroll
                for (int oo = 0; oo < 16; ++oo)
                    mx = fmaxf(mx, b_lds[t * B_PAD + oo]);
                float sum = 0.0f;
                #pragma unroll
                for (int oo = 0; oo < 16; ++oo)
                    sum += __expf(b_lds[t * B_PAD + oo] - mx);
                nmax[t] = mx;
                rden[t] = 1.0f / sum;
            }
            __syncthreads();
        }
    }

    // ---- output ----
    // capsule_poses: [8,15,15,16,4,4] flat: site*256 + o*16 + e
    if (nt < 16) {
        float vout = s[0];
        #pragma unroll
        for (int e = 1; e < 16; ++e) {
            if (nt == e) vout = s[e];
        }
        out[(size_t)site * 256 + o * 16 + nt] = vout;
    } else if (nt == 16) {
        // capsule_activations: [8,15,15,16] after poses (460800 floats)
        float sqv = 0.0f;
        #pragma unroll
        for (int e = 0; e < 16; ++e) sqv += s[e] * s[e];
        out[460800 + (size_t)site * 16 + o] = sqrtf(sqv + 1e-12f);
    }
}

extern "C" void kernel_launch(void* const* d_in, const int* in_sizes, int n_in,
                              void* d_out, int out_size, void* d_ws, size_t ws_size,
                              hipStream_t stream) {
    const float* poses = (const float*)d_in[0];   // [8,32,32,16,4,4] f32
    // d_in[1] = input_activations: unused by the reference computation
    const float* kern  = (const float*)d_in[2];   // [16,3,3,16,4,4] f32
    float* outp = (float*)d_out;                  // 460800 poses + 28800 activations

    convcaps_routing_kernel<<<dim3(8 * OH * OW), dim3(512), 0, stream>>>(
        poses, kern, outp);
}